// Round 12
// baseline (251.539 us; speedup 1.0000x reference)
//
#include <hip/hip_runtime.h>
#include <hip/hip_bf16.h>

typedef __bf16 bf16_t;
typedef __bf16 bf16x8 __attribute__((ext_vector_type(8)));
typedef float  f32x4  __attribute__((ext_vector_type(4)));

constexpr int cB = 8, cS = 512, cD = 2048, cH = 16, cHD = 128;
constexpr int cBS = cB * cS;                         // 4096
constexpr float kInvSqrtHD = 0.08838834764831845f;   // 1/sqrt(128)

__device__ __forceinline__ bf16x8 cvt8(float4 a, float4 b) {
    bf16x8 r;
    r[0]=(bf16_t)a.x; r[1]=(bf16_t)a.y; r[2]=(bf16_t)a.z; r[3]=(bf16_t)a.w;
    r[4]=(bf16_t)b.x; r[5]=(bf16_t)b.y; r[6]=(bf16_t)b.z; r[7]=(bf16_t)b.w;
    return r;
}

__device__ __forceinline__ void gload16(const bf16_t* g, bf16_t* l) {
    __builtin_amdgcn_global_load_lds(
        (const __attribute__((address_space(1))) void*)g,
        (__attribute__((address_space(3))) void*)l,
        16, 0, 0);
}

__device__ __forceinline__ unsigned packbf(float a, float b) {
    const unsigned short ua = __builtin_bit_cast(unsigned short, (bf16_t)a);
    const unsigned short ub = __builtin_bit_cast(unsigned short, (bf16_t)b);
    return (unsigned)ua | ((unsigned)ub << 16);
}
__device__ __forceinline__ float unpk_lo(unsigned u) {
    return (float)__builtin_bit_cast(bf16_t, (unsigned short)(u & 0xffffu));
}
__device__ __forceinline__ float unpk_hi(unsigned u) {
    return (float)__builtin_bit_cast(bf16_t, (unsigned short)(u >> 16));
}

// ---------------- K0: fused fp32->bf16 convert + time/rel softmax -----------
// y=0..2: q/k/v -> abf ; y=3..5: Wq/Wk/Wv -> wbf ; y=6: trattn rows (packed)
__global__ __launch_bounds__(256) void prep_kernel(
    const float* __restrict__ q, const float* __restrict__ k, const float* __restrict__ v,
    const float* __restrict__ wq, const float* __restrict__ wk, const float* __restrict__ wv,
    const float* __restrict__ rel, const float* __restrict__ tsp,
    bf16_t* __restrict__ abf, bf16_t* __restrict__ wbf,
    unsigned* __restrict__ trat)
{
    const int y = blockIdx.y;
    if (y < 6) {
        const float* src; bf16_t* dst; size_t n8;
        if (y < 3) { src = (y==0 ? q : y==1 ? k : v);   dst = abf + (size_t)y*cBS*cD;     n8 = (size_t)cBS*cD/8; }
        else       { src = (y==3 ? wq : y==4 ? wk : wv); dst = wbf + (size_t)(y-3)*cD*cD; n8 = (size_t)cD*cD/8; }
        const size_t stride = (size_t)gridDim.x * blockDim.x;
        for (size_t idx = (size_t)blockIdx.x * blockDim.x + threadIdx.x; idx < n8; idx += stride) {
            const float4 f0 = ((const float4*)src)[2*idx];
            const float4 f1 = ((const float4*)src)[2*idx+1];
            ((bf16x8*)dst)[idx] = cvt8(f0, f1);
        }
        return;
    }
    // ---- trattn: one wave per (b,i) row; writes {t,r} packed per element ----
    const int lane = threadIdx.x & 63;
    const int wid  = threadIdx.x >> 6;
    const int row  = blockIdx.x * 4 + wid;   // 0..4095 = b*S + i
    const int i = row & 511;
    const size_t base = (size_t)row * cS;

    float vt[8], vr[8];
    #pragma unroll
    for (int u = 0; u < 8; ++u) {
        const int j = lane + 64*u;
        const float tv = tsp[base + j];
        const float rv = rel[base + j];
        vt[u] = (j <= i) ? expf(-fabsf(tv)) : -__builtin_inff();
        vr[u] = (j > i && rv != 0.0f) ? rv : -10000.0f;
    }
    float Mt = vt[0], Mr = vr[0];
    #pragma unroll
    for (int u = 1; u < 8; ++u) { Mt = fmaxf(Mt, vt[u]); Mr = fmaxf(Mr, vr[u]); }
    #pragma unroll
    for (int msk = 1; msk < 64; msk <<= 1) {
        Mt = fmaxf(Mt, __shfl_xor(Mt, msk));
        Mr = fmaxf(Mr, __shfl_xor(Mr, msk));
    }
    float St = 0.f, Sr = 0.f;
    #pragma unroll
    for (int u = 0; u < 8; ++u) {
        vt[u] = expf(vt[u] - Mt);
        vr[u] = expf(vr[u] - Mr);
        St += vt[u]; Sr += vr[u];
    }
    #pragma unroll
    for (int msk = 1; msk < 64; msk <<= 1) { St += __shfl_xor(St, msk); Sr += __shfl_xor(Sr, msk); }
    const float rSt = 1.f / St, rSr = 1.f / Sr;
    #pragma unroll
    for (int u = 0; u < 8; ++u) {
        const int j = lane + 64*u;
        trat[base + j] = packbf(vt[u] * rSt, vr[u] * rSr);
    }
}

// ---------------- K1: QKV projection GEMM — 2-phase dbuf, BK=64, 0-conflict -
// T3 minimum recipe: STAGE(t+1) issued BEFORE ds_read+MFMA of tile t; ONE
// __syncthreads (vmcnt0+lgkm drain) per K-tile. Stage latency hides under
// the ~600cy of ds_read+MFMA. Same swizzle as r8 (verified 0 conflicts),
// 64 KiB LDS -> still 2 blocks/CU (matches measured occupancy).
__global__ __launch_bounds__(256) void proj_kernel(
    const bf16_t* __restrict__ abf, const bf16_t* __restrict__ wbf,
    const float* __restrict__ bq, const float* __restrict__ bk, const float* __restrict__ bv,
    bf16_t* __restrict__ qh, bf16_t* __restrict__ kh, bf16_t* __restrict__ vtr)
{
    const int which = blockIdx.y;
    const bf16_t* A = abf + (size_t)which * cBS * cD;
    const bf16_t* W = wbf + (size_t)which * cD * cD;
    const float* bias = (which == 0) ? bq : (which == 1) ? bk : bv;

    const int bm = blockIdx.x & 31;   // 32 M-tiles (M = 4096)
    const int bn = blockIdx.x >> 5;   // 16 N-tiles (N = 2048)
    const int M0 = bm << 7, N0 = bn << 7;

    __shared__ bf16_t As[2][128 * 64];   // 2 x 16 KiB, rows = 128 B
    __shared__ bf16_t Ws[2][128 * 64];   // 2 x 16 KiB

    const int tid = threadIdx.x;
    const int lane = tid & 63, wid = tid >> 6;
    const int wm = wid & 1, wn = wid >> 1;
    const int i15 = lane & 15, g = lane >> 4;

    const int sr0 = tid >> 3;                       // base row (l=0)
    const int sgc = ((tid & 7) ^ (sr0 & 7)) << 3;   // swizzled col (elems)
    const bf16_t* aSrc[4];
    const bf16_t* wSrc[4];
    #pragma unroll
    for (int l = 0; l < 4; ++l) {
        aSrc[l] = A + (size_t)(M0 + l*32 + sr0) * cD + sgc;
        wSrc[l] = W + (size_t)(N0 + l*32 + sr0) * cD + sgc;
    }

    int offA[4], offW[4];
    #pragma unroll
    for (int m = 0; m < 4; ++m) {
        const int r = wm*64 + m*16 + i15;
        offA[m] = r*64 + ((g ^ (r & 7)) << 3);
    }
    #pragma unroll
    for (int n = 0; n < 4; ++n) {
        const int r = wn*64 + n*16 + i15;
        offW[n] = r*64 + ((g ^ (r & 7)) << 3);
    }

    const f32x4 zero4 = {0.f, 0.f, 0.f, 0.f};
    f32x4 acc[4][4];
    #pragma unroll
    for (int m = 0; m < 4; ++m)
        #pragma unroll
        for (int n = 0; n < 4; ++n) acc[m][n] = zero4;

    // prologue: tile 0 -> buf 0, drain
    #pragma unroll
    for (int l = 0; l < 4; ++l) {
        gload16(aSrc[l], &As[0][(l*256 + tid) * 8]);
        gload16(wSrc[l], &Ws[0][(l*256 + tid) * 8]);
    }
    __syncthreads();

    for (int kt = 0; kt < cD / 64; ++kt) {
        const int cur = kt & 1;
        // phase A: issue next tile's staging FIRST (latency hides under MFMA)
        if (kt + 1 < cD / 64) {
            const int kb = (kt + 1) * 64;
            #pragma unroll
            for (int l = 0; l < 4; ++l) {
                gload16(aSrc[l] + kb, &As[cur ^ 1][(l*256 + tid) * 8]);
                gload16(wSrc[l] + kb, &Ws[cur ^ 1][(l*256 + tid) * 8]);
            }
        }
        // phase B: compute tile kt from buf cur
        #pragma unroll
        for (int kk = 0; kk < 2; ++kk) {
            const int x = kk * 32;
            bf16x8 a[4];
            #pragma unroll
            for (int m = 0; m < 4; ++m) a[m] = *(const bf16x8*)(&As[cur][offA[m] ^ x]);
            #pragma unroll
            for (int n = 0; n < 4; ++n) {
                const bf16x8 w = *(const bf16x8*)(&Ws[cur][offW[n] ^ x]);
                #pragma unroll
                for (int m = 0; m < 4; ++m)
                    acc[m][n] = __builtin_amdgcn_mfma_f32_16x16x32_bf16(a[m], w, acc[m][n], 0, 0, 0);
            }
        }
        // ONE barrier per tile: drains vmcnt(0) (next tile landed) and
        // orders this tile's reads before the buffer is overwritten.
        __syncthreads();
    }

    // epilogue: C/D layout col=lane&15, row=(lane>>4)*4+r   [m89-verified]
    #pragma unroll
    for (int n = 0; n < 4; ++n) {
        const int col = N0 + wn*64 + n*16 + i15;
        const float bb = bias[col];
        const int hh = col >> 7, hd = col & 127;
        #pragma unroll
        for (int m = 0; m < 4; ++m) {
            const int rowl = wm*64 + m*16 + (g << 2);
            #pragma unroll
            for (int r = 0; r < 4; ++r) {
                const int R = M0 + rowl + r;
                const int bbi = R >> 9, ss = R & 511;
                const float val = acc[m][n][r] + bb;
                if (which == 2)
                    vtr[((size_t)(bbi*cH + hh) * cHD + hd) * cS + ss] = (bf16_t)val;
                else if (which == 0)
                    qh[((size_t)(bbi*cH + hh) * cS + ss) * cHD + hd] = (bf16_t)val;
                else
                    kh[((size_t)(bbi*cH + hh) * cS + ss) * cHD + hd] = (bf16_t)val;
            }
        }
    }
}

// ---------------- K3: fused attention (round-8 structure, packed t/r) -------
// block = (bh, 64-row i-tile), 4 waves x 16 rows.
// Pass 1 (kt<=itile): QK^T MFMA, exp (no max: scores bounded), e in regs.
// Pass 2 (all 8 kt): mix -> probOut + ps LDS; PV MFMA from double-buffered V
// (gload16, XOR-swizzled both-sides); one barrier/kt, counted vmcnt(16).
__global__ __launch_bounds__(256) void attn_kernel(
    const bf16_t* __restrict__ qh, const bf16_t* __restrict__ kh,
    const bf16_t* __restrict__ vtr,
    const unsigned* __restrict__ trat,
    const float* __restrict__ l1p, const float* __restrict__ l2p,
    float* __restrict__ probOut, float* __restrict__ out)
{
    const int itile = blockIdx.x & 7;
    const int bh = blockIdx.x >> 3;          // b*H + h
    const int b = bh >> 4, h = bh & 15;
    const int i0 = itile * 64;

    const float l1 = l1p[0], l2 = l2p[0];
    const float ap = (1.f - l1) * (1.f - l2);
    const float at = (1.f - l1) * l2;
    const float ar = l1;

    __shared__ bf16_t qps[64][136];  // Q tile, then reused as P (ps) in pass 2
    __shared__ bf16_t ks[64][136];
    __shared__ bf16_t vs[2][128 * 64];  // [hd][j] XOR-swizzled, linear (gload)

    const int tid = threadIdx.x, lane = tid & 63, wid = tid >> 6;
    const int i15 = lane & 15, g = lane >> 4;

    {   // stage q rows i0..i0+63, all 128 d
        const int row = tid >> 2, d0 = (tid & 3) << 5;
        const bf16_t* src = qh + ((size_t)bh * cS + i0 + row) * cHD + d0;
        #pragma unroll
        for (int q = 0; q < 4; ++q)
            *(bf16x8*)(&qps[row][d0 + q*8]) = *(const bf16x8*)(src + q*8);
    }
    __syncthreads();
    bf16x8 aq[4];
    #pragma unroll
    for (int kk = 0; kk < 4; ++kk)
        aq[kk] = *(const bf16x8*)(&qps[wid*16 + i15][kk*32 + (g << 3)]);

    const int iBase = i0 + wid*16 + (g << 2);

    auto stageK = [&](int kt) {
        const int row = tid >> 2, d0 = (tid & 3) << 5;
        const bf16_t* src = kh + ((size_t)bh * cS + kt*64 + row) * cHD + d0;
        #pragma unroll
        for (int q = 0; q < 4; ++q)
            *(bf16x8*)(&ks[row][d0 + q*8]) = *(const bf16x8*)(src + q*8);
    };
    auto stageVissue = [&](int kt, int buf) {
        #pragma unroll
        for (int e4 = 0; e4 < 4; ++e4) {
            const int e = e4 * 256 + tid;              // 0..1023
            const int hd = e >> 3, j8 = e & 7;
            const int jsw = (j8 ^ (hd & 7)) << 3;
            gload16(vtr + ((size_t)bh * cHD + hd) * cS + kt*64 + jsw, &vs[buf][e * 8]);
        }
    };

    // ---- pass 1: exp + row-sum, e kept in registers ----
    float srow[4] = {0.f, 0.f, 0.f, 0.f};
    unsigned es[8][8];
    #pragma unroll
    for (int kt = 0; kt < 8; ++kt) {
        if (kt <= itile) {                 // block-uniform
            __syncthreads();
            stageK(kt);
            __syncthreads();
            f32x4 acc[4];
            const f32x4 zero4 = {0.f, 0.f, 0.f, 0.f};
            #pragma unroll
            for (int n = 0; n < 4; ++n) acc[n] = zero4;
            #pragma unroll
            for (int kk = 0; kk < 4; ++kk)
                #pragma unroll
                for (int n = 0; n < 4; ++n) {
                    bf16x8 bk = *(const bf16x8*)(&ks[n*16 + i15][kk*32 + (g << 3)]);
                    acc[n] = __builtin_amdgcn_mfma_f32_16x16x32_bf16(aq[kk], bk, acc[n], 0, 0, 0);
                }
            #pragma unroll
            for (int n = 0; n < 4; ++n) {
                const int j = kt*64 + n*16 + i15;
                float e[4];
                #pragma unroll
                for (int r = 0; r < 4; ++r) {
                    const int i = iBase + r;
                    e[r] = (j > i) ? 0.f : __expf(acc[n][r] * kInvSqrtHD);
                    srow[r] += e[r];
                }
                es[kt][n*2]     = packbf(e[0], e[1]);
                es[kt][n*2 + 1] = packbf(e[2], e[3]);
            }
        }
    }
    float rs[4];
    #pragma unroll
    for (int r = 0; r < 4; ++r) {
        float s = srow[r];
        #pragma unroll
        for (int msk = 1; msk < 16; msk <<= 1) s += __shfl_xor(s, msk);
        rs[r] = 1.f / s;
    }

    // ---- pass 2: mix -> probOut + ps; PV MFMA; one barrier per kt ----
    f32x4 oacc[8];
    const f32x4 zero4o = {0.f, 0.f, 0.f, 0.f};
    #pragma unroll
    for (int n2 = 0; n2 < 8; ++n2) oacc[n2] = zero4o;

    stageVissue(0, 0);

    #pragma unroll
    for (int kt = 0; kt < 8; ++kt) {
        const bool hasP = (kt <= itile);
        #pragma unroll
        for (int n = 0; n < 4; ++n) {
            float e[4] = {0.f, 0.f, 0.f, 0.f};
            if (hasP) {
                const unsigned p0 = es[kt][n*2], p1 = es[kt][n*2 + 1];
                e[0] = unpk_lo(p0); e[1] = unpk_hi(p0);
                e[2] = unpk_lo(p1); e[3] = unpk_hi(p1);
            }
            const int j = kt*64 + n*16 + i15;
            #pragma unroll
            for (int r = 0; r < 4; ++r) {
                const int i = iBase + r;
                const float p = e[r] * rs[r];
                const size_t tri = (size_t)(b*cS + i) * cS + j;
                const unsigned tr = trat[tri];
                const float tv = unpk_lo(tr);
                const float rv = unpk_hi(tr);
                const float mixed = ap*p + at*tv + ar*rv;
                probOut[((size_t)bh * cS + i) * cS + j] = mixed;
                qps[wid*16 + (g << 2) + r][n*16 + i15] = (bf16_t)mixed;
            }
        }
        // ps write->read is wave-private rows; fence per rule #18
        asm volatile("s_waitcnt lgkmcnt(0)" ::: "memory");
        __builtin_amdgcn_sched_barrier(0);
        // counted wait: V(kt) loads are older than this iter's >=16 newest
        // vmem ops (the probOut stores) -> vmcnt(16) guarantees V landed
        asm volatile("s_waitcnt vmcnt(16)" ::: "memory");
        __builtin_amdgcn_s_barrier();
        // PV: out[64x128] += P[64x64] @ V[64x128]
        #pragma unroll
        for (int kk = 0; kk < 2; ++kk) {
            const bf16x8 pa = *(const bf16x8*)(&qps[wid*16 + i15][kk*32 + (g << 3)]);
            #pragma unroll
            for (int n2 = 0; n2 < 8; ++n2) {
                const int hd = n2*16 + i15;
                const int jb = (kk*64 + g*16) ^ ((hd & 7) << 4);   // byte offset
                const bf16x8 bvv = *(const bf16x8*)((const char*)&vs[kt & 1][0] + hd*128 + jb);
                oacc[n2] = __builtin_amdgcn_mfma_f32_16x16x32_bf16(pa, bvv, oacc[n2], 0, 0, 0);
            }
        }
        if (kt < 7) stageVissue(kt + 1, (kt + 1) & 1);
    }

    // ---- out write: D layout col=i15, row=g*4+r ----
    #pragma unroll
    for (int n2 = 0; n2 < 8; ++n2) {
        const int hd = n2*16 + i15;
        #pragma unroll
        for (int r = 0; r < 4; ++r) {
            const int i = i0 + wid*16 + (g << 2) + r;
            out[(size_t)(b*cS + i) * cD + h*cHD + hd] = oacc[n2][r];
        }
    }
}

extern "C" void kernel_launch(void* const* d_in, const int* in_sizes, int n_in,
                              void* d_out, int out_size, void* d_ws, size_t ws_size,
                              hipStream_t stream)
{
    const float* query = (const float*)d_in[0];
    const float* keyi  = (const float*)d_in[1];
    const float* value = (const float*)d_in[2];
    const float* rel   = (const float*)d_in[3];
    const float* l1    = (const float*)d_in[4];
    const float* l2    = (const float*)d_in[5];
    const float* tsp   = (const float*)d_in[6];
    // d_in[7] pos_key_embeds, d_in[8] pos_value_embeds, d_in[9] mask: unused
    const float* Wq    = (const float*)d_in[10];
    const float* bq    = (const float*)d_in[11];
    const float* Wk    = (const float*)d_in[12];
    const float* bk    = (const float*)d_in[13];
    const float* Wv    = (const float*)d_in[14];
    const float* bv    = (const float*)d_in[15];

    char* ws = (char*)d_ws;
    const size_t projBytes = (size_t)cB * cH * cS * cHD * 2;   // 16 MiB each
    bf16_t* qh  = (bf16_t*)(ws);
    bf16_t* kh  = (bf16_t*)(ws + projBytes);
    bf16_t* vtr = (bf16_t*)(ws + 2 * projBytes);
    unsigned* trat = (unsigned*)(ws + 3 * projBytes);          // 8 MiB packed {t,r}

    float* out = (float*)d_out;
    float* probOut = out + (size_t)cB * cS * cD;   // output 1 starts after out

    // bf16 staging copies live in the probOut region of d_out: proj consumes
    // them strictly before attn_kernel overwrites that region (stream order).
    bf16_t* abf = (bf16_t*)probOut;                                 // 48 MiB
    bf16_t* wbf = abf + (size_t)3 * cBS * cD;                       // 24 MiB  (< 134 MiB region)

    prep_kernel<<<dim3(1024, 7), 256, 0, stream>>>(query, keyi, value, Wq, Wk, Wv,
                                                   rel, tsp, abf, wbf, trat);
    proj_kernel<<<dim3(512, 3), 256, 0, stream>>>(abf, wbf, bq, bk, bv, qh, kh, vtr);
    attn_kernel<<<cB * cH * (cS / 64), 256, 0, stream>>>(qh, kh, vtr, trat, l1, l2, probOut, out);
}

// Round 13
// 241.800 us; speedup vs baseline: 1.0403x; 1.0403x over previous
//
#include <hip/hip_runtime.h>
#include <hip/hip_bf16.h>

typedef __bf16 bf16_t;
typedef __bf16 bf16x8 __attribute__((ext_vector_type(8)));
typedef float  f32x4  __attribute__((ext_vector_type(4)));

constexpr int cB = 8, cS = 512, cD = 2048, cH = 16, cHD = 128;
constexpr int cBS = cB * cS;                         // 4096
constexpr float kInvSqrtHD = 0.08838834764831845f;   // 1/sqrt(128)

__device__ __forceinline__ bf16x8 cvt8(float4 a, float4 b) {
    bf16x8 r;
    r[0]=(bf16_t)a.x; r[1]=(bf16_t)a.y; r[2]=(bf16_t)a.z; r[3]=(bf16_t)a.w;
    r[4]=(bf16_t)b.x; r[5]=(bf16_t)b.y; r[6]=(bf16_t)b.z; r[7]=(bf16_t)b.w;
    return r;
}

__device__ __forceinline__ void gload16(const bf16_t* g, bf16_t* l) {
    __builtin_amdgcn_global_load_lds(
        (const __attribute__((address_space(1))) void*)g,
        (__attribute__((address_space(3))) void*)l,
        16, 0, 0);
}

__device__ __forceinline__ unsigned packbf(float a, float b) {
    const unsigned short ua = __builtin_bit_cast(unsigned short, (bf16_t)a);
    const unsigned short ub = __builtin_bit_cast(unsigned short, (bf16_t)b);
    return (unsigned)ua | ((unsigned)ub << 16);
}
__device__ __forceinline__ float unpk_lo(unsigned u) {
    return (float)__builtin_bit_cast(bf16_t, (unsigned short)(u & 0xffffu));
}
__device__ __forceinline__ float unpk_hi(unsigned u) {
    return (float)__builtin_bit_cast(bf16_t, (unsigned short)(u >> 16));
}

// ---------------- K0: fused fp32->bf16 convert + time/rel softmax -----------
// y=0..2: q/k/v -> abf ; y=3..5: Wq/Wk/Wv -> wbf ; y=6: trattn rows (packed)
__global__ __launch_bounds__(256) void prep_kernel(
    const float* __restrict__ q, const float* __restrict__ k, const float* __restrict__ v,
    const float* __restrict__ wq, const float* __restrict__ wk, const float* __restrict__ wv,
    const float* __restrict__ rel, const float* __restrict__ tsp,
    bf16_t* __restrict__ abf, bf16_t* __restrict__ wbf,
    unsigned* __restrict__ trat)
{
    const int y = blockIdx.y;
    if (y < 6) {
        const float* src; bf16_t* dst; size_t n8;
        if (y < 3) { src = (y==0 ? q : y==1 ? k : v);   dst = abf + (size_t)y*cBS*cD;     n8 = (size_t)cBS*cD/8; }
        else       { src = (y==3 ? wq : y==4 ? wk : wv); dst = wbf + (size_t)(y-3)*cD*cD; n8 = (size_t)cD*cD/8; }
        const size_t stride = (size_t)gridDim.x * blockDim.x;
        for (size_t idx = (size_t)blockIdx.x * blockDim.x + threadIdx.x; idx < n8; idx += stride) {
            const float4 f0 = ((const float4*)src)[2*idx];
            const float4 f1 = ((const float4*)src)[2*idx+1];
            ((bf16x8*)dst)[idx] = cvt8(f0, f1);
        }
        return;
    }
    // ---- trattn: one wave per (b,i) row; writes {t,r} packed per element ----
    const int lane = threadIdx.x & 63;
    const int wid  = threadIdx.x >> 6;
    const int row  = blockIdx.x * 4 + wid;   // 0..4095 = b*S + i
    const int i = row & 511;
    const size_t base = (size_t)row * cS;

    float vt[8], vr[8];
    #pragma unroll
    for (int u = 0; u < 8; ++u) {
        const int j = lane + 64*u;
        const float tv = tsp[base + j];
        const float rv = rel[base + j];
        vt[u] = (j <= i) ? expf(-fabsf(tv)) : -__builtin_inff();
        vr[u] = (j > i && rv != 0.0f) ? rv : -10000.0f;
    }
    float Mt = vt[0], Mr = vr[0];
    #pragma unroll
    for (int u = 1; u < 8; ++u) { Mt = fmaxf(Mt, vt[u]); Mr = fmaxf(Mr, vr[u]); }
    #pragma unroll
    for (int msk = 1; msk < 64; msk <<= 1) {
        Mt = fmaxf(Mt, __shfl_xor(Mt, msk));
        Mr = fmaxf(Mr, __shfl_xor(Mr, msk));
    }
    float St = 0.f, Sr = 0.f;
    #pragma unroll
    for (int u = 0; u < 8; ++u) {
        vt[u] = expf(vt[u] - Mt);
        vr[u] = expf(vr[u] - Mr);
        St += vt[u]; Sr += vr[u];
    }
    #pragma unroll
    for (int msk = 1; msk < 64; msk <<= 1) { St += __shfl_xor(St, msk); Sr += __shfl_xor(Sr, msk); }
    const float rSt = 1.f / St, rSr = 1.f / Sr;
    #pragma unroll
    for (int u = 0; u < 8; ++u) {
        const int j = lane + 64*u;
        trat[base + j] = packbf(vt[u] * rSt, vr[u] * rSr);
    }
}

// ---------------- K1: QKV projection GEMM — BK=64, 128B rows, 0-conflict ----
// (round-8/11 kernel: 2-barrier schedule, single-buffered, verified 0 bank
// conflicts via pre-swizzled source + XOR'd frag reads. Measured best.)
__global__ __launch_bounds__(256) void proj_kernel(
    const bf16_t* __restrict__ abf, const bf16_t* __restrict__ wbf,
    const float* __restrict__ bq, const float* __restrict__ bk, const float* __restrict__ bv,
    bf16_t* __restrict__ qh, bf16_t* __restrict__ kh, bf16_t* __restrict__ vtr)
{
    const int which = blockIdx.y;
    const bf16_t* A = abf + (size_t)which * cBS * cD;
    const bf16_t* W = wbf + (size_t)which * cD * cD;
    const float* bias = (which == 0) ? bq : (which == 1) ? bk : bv;

    const int bm = blockIdx.x & 31;   // 32 M-tiles (M = 4096)
    const int bn = blockIdx.x >> 5;   // 16 N-tiles (N = 2048)
    const int M0 = bm << 7, N0 = bn << 7;

    __shared__ bf16_t As[128 * 64];   // 16 KiB, rows = 128 B
    __shared__ bf16_t Ws[128 * 64];   // 16 KiB

    const int tid = threadIdx.x;
    const int lane = tid & 63, wid = tid >> 6;
    const int wm = wid & 1, wn = wid >> 1;
    const int i15 = lane & 15, g = lane >> 4;

    const int sr0 = tid >> 3;                       // base row (l=0)
    const int sgc = ((tid & 7) ^ (sr0 & 7)) << 3;   // swizzled col (elems)
    const bf16_t* aSrc[4];
    const bf16_t* wSrc[4];
    #pragma unroll
    for (int l = 0; l < 4; ++l) {
        aSrc[l] = A + (size_t)(M0 + l*32 + sr0) * cD + sgc;
        wSrc[l] = W + (size_t)(N0 + l*32 + sr0) * cD + sgc;
    }

    int offA[4], offW[4];
    #pragma unroll
    for (int m = 0; m < 4; ++m) {
        const int r = wm*64 + m*16 + i15;
        offA[m] = r*64 + ((g ^ (r & 7)) << 3);
    }
    #pragma unroll
    for (int n = 0; n < 4; ++n) {
        const int r = wn*64 + n*16 + i15;
        offW[n] = r*64 + ((g ^ (r & 7)) << 3);
    }

    const f32x4 zero4 = {0.f, 0.f, 0.f, 0.f};
    f32x4 acc[4][4];
    #pragma unroll
    for (int m = 0; m < 4; ++m)
        #pragma unroll
        for (int n = 0; n < 4; ++n) acc[m][n] = zero4;

    for (int kt = 0; kt < cD / 64; ++kt) {
        const int kb = kt * 64;
        __syncthreads();
        #pragma unroll
        for (int l = 0; l < 4; ++l) {
            gload16(aSrc[l] + kb, &As[(l*256 + tid) * 8]);
            gload16(wSrc[l] + kb, &Ws[(l*256 + tid) * 8]);
        }
        __syncthreads();   // compiler drains vmcnt before barrier
        #pragma unroll
        for (int kk = 0; kk < 2; ++kk) {
            const int x = kk * 32;
            bf16x8 a[4];
            #pragma unroll
            for (int m = 0; m < 4; ++m) a[m] = *(const bf16x8*)(&As[offA[m] ^ x]);
            #pragma unroll
            for (int n = 0; n < 4; ++n) {
                const bf16x8 w = *(const bf16x8*)(&Ws[offW[n] ^ x]);
                #pragma unroll
                for (int m = 0; m < 4; ++m)
                    acc[m][n] = __builtin_amdgcn_mfma_f32_16x16x32_bf16(a[m], w, acc[m][n], 0, 0, 0);
            }
        }
    }

    // epilogue: C/D layout col=lane&15, row=(lane>>4)*4+r   [m89-verified]
    #pragma unroll
    for (int n = 0; n < 4; ++n) {
        const int col = N0 + wn*64 + n*16 + i15;
        const float bb = bias[col];
        const int hh = col >> 7, hd = col & 127;
        #pragma unroll
        for (int m = 0; m < 4; ++m) {
            const int rowl = wm*64 + m*16 + (g << 2);
            #pragma unroll
            for (int r = 0; r < 4; ++r) {
                const int R = M0 + rowl + r;
                const int bbi = R >> 9, ss = R & 511;
                const float val = acc[m][n][r] + bb;
                if (which == 2)
                    vtr[((size_t)(bbi*cH + hh) * cHD + hd) * cS + ss] = (bf16_t)val;
                else if (which == 0)
                    qh[((size_t)(bbi*cH + hh) * cS + ss) * cHD + hd] = (bf16_t)val;
                else
                    kh[((size_t)(bbi*cH + hh) * cS + ss) * cHD + hd] = (bf16_t)val;
            }
        }
    }
}

// ---------------- K3: fused attention (round-8 structure, packed t/r) -------
// block = (bh, 64-row i-tile), 4 waves x 16 rows.
// Pass 1 (kt<=itile): QK^T MFMA, exp (no max: scores bounded), e in regs.
// Pass 2 (all 8 kt): mix -> probOut + ps LDS; PV MFMA from double-buffered V
// (gload16, XOR-swizzled both-sides); one barrier/kt, counted vmcnt(16).
__global__ __launch_bounds__(256) void attn_kernel(
    const bf16_t* __restrict__ qh, const bf16_t* __restrict__ kh,
    const bf16_t* __restrict__ vtr,
    const unsigned* __restrict__ trat,
    const float* __restrict__ l1p, const float* __restrict__ l2p,
    float* __restrict__ probOut, float* __restrict__ out)
{
    const int itile = blockIdx.x & 7;
    const int bh = blockIdx.x >> 3;          // b*H + h
    const int b = bh >> 4, h = bh & 15;
    const int i0 = itile * 64;

    const float l1 = l1p[0], l2 = l2p[0];
    const float ap = (1.f - l1) * (1.f - l2);
    const float at = (1.f - l1) * l2;
    const float ar = l1;

    __shared__ bf16_t qps[64][136];  // Q tile, then reused as P (ps) in pass 2
    __shared__ bf16_t ks[64][136];
    __shared__ bf16_t vs[2][128 * 64];  // [hd][j] XOR-swizzled, linear (gload)

    const int tid = threadIdx.x, lane = tid & 63, wid = tid >> 6;
    const int i15 = lane & 15, g = lane >> 4;

    {   // stage q rows i0..i0+63, all 128 d
        const int row = tid >> 2, d0 = (tid & 3) << 5;
        const bf16_t* src = qh + ((size_t)bh * cS + i0 + row) * cHD + d0;
        #pragma unroll
        for (int q = 0; q < 4; ++q)
            *(bf16x8*)(&qps[row][d0 + q*8]) = *(const bf16x8*)(src + q*8);
    }
    __syncthreads();
    bf16x8 aq[4];
    #pragma unroll
    for (int kk = 0; kk < 4; ++kk)
        aq[kk] = *(const bf16x8*)(&qps[wid*16 + i15][kk*32 + (g << 3)]);

    const int iBase = i0 + wid*16 + (g << 2);

    auto stageK = [&](int kt) {
        const int row = tid >> 2, d0 = (tid & 3) << 5;
        const bf16_t* src = kh + ((size_t)bh * cS + kt*64 + row) * cHD + d0;
        #pragma unroll
        for (int q = 0; q < 4; ++q)
            *(bf16x8*)(&ks[row][d0 + q*8]) = *(const bf16x8*)(src + q*8);
    };
    auto stageVissue = [&](int kt, int buf) {
        #pragma unroll
        for (int e4 = 0; e4 < 4; ++e4) {
            const int e = e4 * 256 + tid;              // 0..1023
            const int hd = e >> 3, j8 = e & 7;
            const int jsw = (j8 ^ (hd & 7)) << 3;
            gload16(vtr + ((size_t)bh * cHD + hd) * cS + kt*64 + jsw, &vs[buf][e * 8]);
        }
    };

    // ---- pass 1: exp + row-sum, e kept in registers ----
    float srow[4] = {0.f, 0.f, 0.f, 0.f};
    unsigned es[8][8];
    #pragma unroll
    for (int kt = 0; kt < 8; ++kt) {
        if (kt <= itile) {                 // block-uniform
            __syncthreads();
            stageK(kt);
            __syncthreads();
            f32x4 acc[4];
            const f32x4 zero4 = {0.f, 0.f, 0.f, 0.f};
            #pragma unroll
            for (int n = 0; n < 4; ++n) acc[n] = zero4;
            #pragma unroll
            for (int kk = 0; kk < 4; ++kk)
                #pragma unroll
                for (int n = 0; n < 4; ++n) {
                    bf16x8 bk = *(const bf16x8*)(&ks[n*16 + i15][kk*32 + (g << 3)]);
                    acc[n] = __builtin_amdgcn_mfma_f32_16x16x32_bf16(aq[kk], bk, acc[n], 0, 0, 0);
                }
            #pragma unroll
            for (int n = 0; n < 4; ++n) {
                const int j = kt*64 + n*16 + i15;
                float e[4];
                #pragma unroll
                for (int r = 0; r < 4; ++r) {
                    const int i = iBase + r;
                    e[r] = (j > i) ? 0.f : __expf(acc[n][r] * kInvSqrtHD);
                    srow[r] += e[r];
                }
                es[kt][n*2]     = packbf(e[0], e[1]);
                es[kt][n*2 + 1] = packbf(e[2], e[3]);
            }
        }
    }
    float rs[4];
    #pragma unroll
    for (int r = 0; r < 4; ++r) {
        float s = srow[r];
        #pragma unroll
        for (int msk = 1; msk < 16; msk <<= 1) s += __shfl_xor(s, msk);
        rs[r] = 1.f / s;
    }

    // ---- pass 2: mix -> probOut + ps; PV MFMA; one barrier per kt ----
    f32x4 oacc[8];
    const f32x4 zero4o = {0.f, 0.f, 0.f, 0.f};
    #pragma unroll
    for (int n2 = 0; n2 < 8; ++n2) oacc[n2] = zero4o;

    stageVissue(0, 0);

    #pragma unroll
    for (int kt = 0; kt < 8; ++kt) {
        const bool hasP = (kt <= itile);
        #pragma unroll
        for (int n = 0; n < 4; ++n) {
            float e[4] = {0.f, 0.f, 0.f, 0.f};
            if (hasP) {
                const unsigned p0 = es[kt][n*2], p1 = es[kt][n*2 + 1];
                e[0] = unpk_lo(p0); e[1] = unpk_hi(p0);
                e[2] = unpk_lo(p1); e[3] = unpk_hi(p1);
            }
            const int j = kt*64 + n*16 + i15;
            #pragma unroll
            for (int r = 0; r < 4; ++r) {
                const int i = iBase + r;
                const float p = e[r] * rs[r];
                const size_t tri = (size_t)(b*cS + i) * cS + j;
                const unsigned tr = trat[tri];
                const float tv = unpk_lo(tr);
                const float rv = unpk_hi(tr);
                const float mixed = ap*p + at*tv + ar*rv;
                probOut[((size_t)bh * cS + i) * cS + j] = mixed;
                qps[wid*16 + (g << 2) + r][n*16 + i15] = (bf16_t)mixed;
            }
        }
        // ps write->read is wave-private rows; fence per rule #18
        asm volatile("s_waitcnt lgkmcnt(0)" ::: "memory");
        __builtin_amdgcn_sched_barrier(0);
        // counted wait: V(kt) loads are older than this iter's >=16 newest
        // vmem ops (the probOut stores) -> vmcnt(16) guarantees V landed
        asm volatile("s_waitcnt vmcnt(16)" ::: "memory");
        __builtin_amdgcn_s_barrier();
        // PV: out[64x128] += P[64x64] @ V[64x128]
        #pragma unroll
        for (int kk = 0; kk < 2; ++kk) {
            const bf16x8 pa = *(const bf16x8*)(&qps[wid*16 + i15][kk*32 + (g << 3)]);
            #pragma unroll
            for (int n2 = 0; n2 < 8; ++n2) {
                const int hd = n2*16 + i15;
                const int jb = (kk*64 + g*16) ^ ((hd & 7) << 4);   // byte offset
                const bf16x8 bvv = *(const bf16x8*)((const char*)&vs[kt & 1][0] + hd*128 + jb);
                oacc[n2] = __builtin_amdgcn_mfma_f32_16x16x32_bf16(pa, bvv, oacc[n2], 0, 0, 0);
            }
        }
        if (kt < 7) stageVissue(kt + 1, (kt + 1) & 1);
    }

    // ---- out write: D layout col=i15, row=g*4+r ----
    #pragma unroll
    for (int n2 = 0; n2 < 8; ++n2) {
        const int hd = n2*16 + i15;
        #pragma unroll
        for (int r = 0; r < 4; ++r) {
            const int i = i0 + wid*16 + (g << 2) + r;
            out[(size_t)(b*cS + i) * cD + h*cHD + hd] = oacc[n2][r];
        }
    }
}

extern "C" void kernel_launch(void* const* d_in, const int* in_sizes, int n_in,
                              void* d_out, int out_size, void* d_ws, size_t ws_size,
                              hipStream_t stream)
{
    const float* query = (const float*)d_in[0];
    const float* keyi  = (const float*)d_in[1];
    const float* value = (const float*)d_in[2];
    const float* rel   = (const float*)d_in[3];
    const float* l1    = (const float*)d_in[4];
    const float* l2    = (const float*)d_in[5];
    const float* tsp   = (const float*)d_in[6];
    // d_in[7] pos_key_embeds, d_in[8] pos_value_embeds, d_in[9] mask: unused
    const float* Wq    = (const float*)d_in[10];
    const float* bq    = (const float*)d_in[11];
    const float* Wk    = (const float*)d_in[12];
    const float* bk    = (const float*)d_in[13];
    const float* Wv    = (const float*)d_in[14];
    const float* bv    = (const float*)d_in[15];

    char* ws = (char*)d_ws;
    const size_t projBytes = (size_t)cB * cH * cS * cHD * 2;   // 16 MiB each
    bf16_t* qh  = (bf16_t*)(ws);
    bf16_t* kh  = (bf16_t*)(ws + projBytes);
    bf16_t* vtr = (bf16_t*)(ws + 2 * projBytes);
    unsigned* trat = (unsigned*)(ws + 3 * projBytes);          // 8 MiB packed {t,r}

    float* out = (float*)d_out;
    float* probOut = out + (size_t)cB * cS * cD;   // output 1 starts after out

    // bf16 staging copies live in the probOut region of d_out: proj consumes
    // them strictly before attn_kernel overwrites that region (stream order).
    bf16_t* abf = (bf16_t*)probOut;                                 // 48 MiB
    bf16_t* wbf = abf + (size_t)3 * cBS * cD;                       // 24 MiB  (< 134 MiB region)

    prep_kernel<<<dim3(1024, 7), 256, 0, stream>>>(query, keyi, value, Wq, Wk, Wv,
                                                   rel, tsp, abf, wbf, trat);
    proj_kernel<<<dim3(512, 3), 256, 0, stream>>>(abf, wbf, bq, bk, bv, qh, kh, vtr);
    attn_kernel<<<cB * cH * (cS / 64), 256, 0, stream>>>(qh, kh, vtr, trat, l1, l2, probOut, out);
}